// Round 2
// baseline (322.134 us; speedup 1.0000x reference)
//
#include <hip/hip_runtime.h>

// Problem constants
#define NROWS   200000
#define TILE    32                  // rows (n) per block
#define NBLOCKS (NROWS / TILE)      // 6250, exact

typedef __attribute__((ext_vector_type(4))) float f32x4;
typedef __attribute__((ext_vector_type(8))) short bf16x8;

// fp32 -> bf16 round-to-nearest-even (bit trick; inputs finite)
__device__ __forceinline__ unsigned short f2bf(float f) {
  unsigned b = __float_as_uint(f);
  b += 0x7fffu + ((b >> 16) & 1u);
  return (unsigned short)(b >> 16);
}
__device__ __forceinline__ float bf2f(unsigned short s) {
  return __uint_as_float((unsigned)s << 16);
}
__device__ __forceinline__ unsigned pack2(float lo, float hi) {
  return (unsigned)f2bf(lo) | ((unsigned)f2bf(hi) << 16);
}
__device__ __forceinline__ f32x4 mfma16(bf16x8 a, bf16x8 b, f32x4 c) {
  return __builtin_amdgcn_mfma_f32_16x16x32_bf16(a, b, c, 0, 0, 0);
}
__device__ __forceinline__ float fast_tanh(float x) {
  float e = __expf(2.0f * x);
  return 1.0f - __fdividef(2.0f, e + 1.0f);
}
// LDS XOR swizzle: all regions use 256B row pitch; row = byte>>8.
// XOR bits 4..6 with (row&7): ds_read_b128 A-fragments (16 rows, fixed col)
// spread across 8 distinct 16B slots -> <=2-way bank aliasing (free, m136).
// Pure function of the final byte offset -> write/read always consistent.
__device__ __forceinline__ int SW(int b) { return b ^ (((b >> 8) & 7) << 4); }

// ---------------------------------------------------------------------------
// Weight prep (unchanged ordering): W[K][Nout] fp32 -> bf16 MFMA-B fragments.
// Fragment (kt,nt) at index kt*NT+nt: lane l elem i <- W[kt*32+8*(l>>4)+i][nt*16+(l&15)]
// ---------------------------------------------------------------------------
__global__ void prep_weights(const float* __restrict__ Wp,
                             const float* __restrict__ W1,
                             const float* __restrict__ W2,
                             unsigned short* __restrict__ wpf,
                             unsigned short* __restrict__ w1f,
                             unsigned short* __restrict__ w2f) {
  int t = blockIdx.x * 256 + threadIdx.x;   // 72*256 = 18432 = 288*64
  int q = t >> 6, l = t & 63;
  const float* W; unsigned short* dst; int NT, Nout, qb;
  if (q < 32)       { W = Wp; dst = wpf; NT = 8;  Nout = 128; qb = q; }
  else if (q < 160) { W = W1; dst = w1f; NT = 32; Nout = 512; qb = q - 32; }
  else              { W = W2; dst = w2f; NT = 8;  Nout = 128; qb = q - 160; }
  int kt = qb / NT, nt = qb % NT;
  int row0 = kt * 32 + 8 * (l >> 4);
  int col  = nt * 16 + (l & 15);
  unsigned short v[8];
#pragma unroll
  for (int i = 0; i < 8; ++i) v[i] = f2bf(W[(row0 + i) * Nout + col]);
  uint4 pack;
  pack.x = (unsigned)v[0] | ((unsigned)v[1] << 16);
  pack.y = (unsigned)v[2] | ((unsigned)v[3] << 16);
  pack.z = (unsigned)v[4] | ((unsigned)v[5] << 16);
  pack.w = (unsigned)v[6] | ((unsigned)v[7] << 16);
  *(uint4*)(dst + (size_t)(qb * 64 + l) * 8) = pack;
}

// ---------------------------------------------------------------------------
// Fused kernel, 32 rows / 256 threads (4 waves), LDS = 32768 B exactly
//  -> 4-5 blocks/CU (vs 2 before).
// LDS map (all 256B row pitch, SW-swizzled):
//   [0,     24576): x bf16 [96 rows'=3n+d][128]   (dead after GEMM1)
//       reused:  [0,8192)     h1 chunk bf16 [32][128]
//                [8192,16384) h2 bf16 [32][128]
//   [24576, 32768): c bf16 [32][128]
// K-chunked MLP: for ch=0..3, GEMM2 computes h1[:,128ch:128ch+128] (tanh'd),
// GEMM3 accumulates its K-slice into acc3 (regs). Weights are read from L2
// exactly once per block (wave w owns n-tiles {2w,2w+1} in every GEMM).
// GEMM1 accumulators packed to bf16 pairs (24 VGPRs) to keep peak regs ~100.
// ---------------------------------------------------------------------------
__global__ __launch_bounds__(256, 4) void fused_kernel(
    const float* __restrict__ x,
    const float* __restrict__ b1,
    const float* __restrict__ b2,
    const unsigned short* __restrict__ wpf,
    const unsigned short* __restrict__ w1f,
    const unsigned short* __restrict__ w2f,
    float* __restrict__ out) {
  __shared__ __align__(16) char smem[32768];
  const int t = threadIdx.x;
  const int l = t & 63;
  const int w = t >> 6;
  const int lr = l & 15;     // lane row-in-tile (A) / col (B,D)
  const int lq = l >> 4;     // lane quad
  const long n0 = (long)blockIdx.x * TILE;

  // ---- P0: stage x -> bf16 LDS; c = sum_d x^2 in fp32 from un-rounded x.
  {
    float4 v[4][3];
#pragma unroll
    for (int k = 0; k < 4; ++k) {
      int p = t + k * 256, r = p >> 5, f = (p & 31) * 4;
      const float* xp = x + (n0 + r) * 384 + f;
      v[k][0] = *(const float4*)(xp);
      v[k][1] = *(const float4*)(xp + 128);
      v[k][2] = *(const float4*)(xp + 256);
    }
#pragma unroll
    for (int k = 0; k < 4; ++k) {
      int p = t + k * 256, r = p >> 5, f = (p & 31) * 4;
      float4 a = v[k][0], b = v[k][1], c = v[k][2];
      ushort4 s0 = { f2bf(a.x), f2bf(a.y), f2bf(a.z), f2bf(a.w) };
      ushort4 s1 = { f2bf(b.x), f2bf(b.y), f2bf(b.z), f2bf(b.w) };
      ushort4 s2 = { f2bf(c.x), f2bf(c.y), f2bf(c.z), f2bf(c.w) };
      ushort4 sc = { f2bf(a.x*a.x + b.x*b.x + c.x*c.x),
                     f2bf(a.y*a.y + b.y*b.y + c.y*c.y),
                     f2bf(a.z*a.z + b.z*b.z + c.z*c.z),
                     f2bf(a.w*a.w + b.w*b.w + c.w*c.w) };
      *(ushort4*)(smem + SW((3 * r + 0) * 256 + f * 2)) = s0;
      *(ushort4*)(smem + SW((3 * r + 1) * 256 + f * 2)) = s1;
      *(ushort4*)(smem + SW((3 * r + 2) * 256 + f * 2)) = s2;
      *(ushort4*)(smem + SW(24576 + r * 256 + f * 2))   = sc;
    }
  }
  __syncthreads();

  // ---- GEMM1: linx[r'][g] = x[r'][:] @ Wp[:][g].  96x128; wave w owns
  // n-tiles {2w,2w+1} x 6 m-tiles. Result packed to bf16 pairs immediately.
  unsigned lx[6][2][2];
  {
    f32x4 acc1[6][2] = {};
#pragma unroll
    for (int kt = 0; kt < 4; ++kt) {
      bf16x8 a[6];
#pragma unroll
      for (int mt = 0; mt < 6; ++mt)
        a[mt] = *(const bf16x8*)(smem + SW((mt * 16 + lr) * 256 + kt * 64 + lq * 16));
#pragma unroll
      for (int jj = 0; jj < 2; ++jj) {
        bf16x8 b = *(const bf16x8*)(wpf + (size_t)((kt * 8 + 2 * w + jj) * 64 + l) * 8);
#pragma unroll
        for (int mt = 0; mt < 6; ++mt) acc1[mt][jj] = mfma16(a[mt], b, acc1[mt][jj]);
      }
    }
#pragma unroll
    for (int mt = 0; mt < 6; ++mt)
#pragma unroll
      for (int jj = 0; jj < 2; ++jj) {
        lx[mt][jj][0] = pack2(acc1[mt][jj][0], acc1[mt][jj][1]);
        lx[mt][jj][1] = pack2(acc1[mt][jj][2], acc1[mt][jj][3]);
      }
  }
  __syncthreads();   // x region dead; h1/h2 reuse begins

  // ---- MLP, K-chunked: ch covers h1 cols [128ch, 128ch+128)
  f32x4 acc3[2][2] = {};
#pragma unroll
  for (int ch = 0; ch < 4; ++ch) {
    // GEMM2 chunk: h1c = tanh(c @ W1[:,chunk] + b1[chunk])
    f32x4 acc2[2][2] = {};
#pragma unroll
    for (int kt = 0; kt < 4; ++kt) {
      bf16x8 a2[2];
#pragma unroll
      for (int mt = 0; mt < 2; ++mt)
        a2[mt] = *(const bf16x8*)(smem + SW(24576 + (mt * 16 + lr) * 256 + kt * 64 + lq * 16));
#pragma unroll
      for (int jj = 0; jj < 2; ++jj) {
        bf16x8 b = *(const bf16x8*)(w1f + (size_t)((kt * 32 + ch * 8 + 2 * w + jj) * 64 + l) * 8);
#pragma unroll
        for (int mt = 0; mt < 2; ++mt) acc2[mt][jj] = mfma16(a2[mt], b, acc2[mt][jj]);
      }
    }
    // epilogue: bias + tanh -> h1c LDS (u16 scatter, swizzled)
#pragma unroll
    for (int jj = 0; jj < 2; ++jj) {
      int col = (2 * w + jj) * 16 + lr;
      float b1v = b1[ch * 128 + col];
#pragma unroll
      for (int mt = 0; mt < 2; ++mt)
#pragma unroll
        for (int reg = 0; reg < 4; ++reg) {
          int row = mt * 16 + 4 * lq + reg;
          *(unsigned short*)(smem + SW(row * 256 + col * 2)) =
              f2bf(fast_tanh(acc2[mt][jj][reg] + b1v));
        }
    }
    __syncthreads();
    // GEMM3 partial: acc3 += h1c @ W2[K-slice,:]
#pragma unroll
    for (int kt = 0; kt < 4; ++kt) {
      bf16x8 a3[2];
#pragma unroll
      for (int mt = 0; mt < 2; ++mt)
        a3[mt] = *(const bf16x8*)(smem + SW((mt * 16 + lr) * 256 + kt * 64 + lq * 16));
#pragma unroll
      for (int jj = 0; jj < 2; ++jj) {
        bf16x8 b = *(const bf16x8*)(w2f + (size_t)(((ch * 4 + kt) * 8 + 2 * w + jj) * 64 + l) * 8);
#pragma unroll
        for (int mt = 0; mt < 2; ++mt) acc3[mt][jj] = mfma16(a3[mt], b, acc3[mt][jj]);
      }
    }
    __syncthreads();   // h1c reads done before next chunk overwrites
  }

  // ---- h2 = acc3 + b2 -> bf16 LDS [32][128] at offset 8192
#pragma unroll
  for (int jj = 0; jj < 2; ++jj) {
    int col = (2 * w + jj) * 16 + lr;
    float b2v = b2[col];
#pragma unroll
    for (int mt = 0; mt < 2; ++mt)
#pragma unroll
      for (int reg = 0; reg < 4; ++reg) {
        int row = mt * 16 + 4 * lq + reg;
        *(unsigned short*)(smem + SW(8192 + row * 256 + col * 2)) =
            f2bf(acc3[mt][jj][reg] + b2v);
      }
  }
  __syncthreads();

  // ---- Final: out[n,d,g] = linx[r'][g] * h2[n][g],  r' = 3n+d
#pragma unroll
  for (int mt = 0; mt < 6; ++mt)
#pragma unroll
    for (int jj = 0; jj < 2; ++jj) {
      int g = (2 * w + jj) * 16 + lr;
#pragma unroll
      for (int reg = 0; reg < 4; ++reg) {
        int rp = mt * 16 + 4 * lq + reg;
        int n = rp / 3;   // magic-mul
        unsigned short hv = *(const unsigned short*)(smem + SW(8192 + n * 256 + g * 2));
        unsigned pk = lx[mt][jj][reg >> 1];
        float lv = __uint_as_float((reg & 1) ? (pk & 0xffff0000u) : (pk << 16));
        out[n0 * 384 + (long)rp * 128 + g] = lv * bf2f(hv);
      }
    }
}

extern "C" void kernel_launch(void* const* d_in, const int* in_sizes, int n_in,
                              void* d_out, int out_size, void* d_ws, size_t ws_size,
                              hipStream_t stream) {
  const float* x  = (const float*)d_in[0];
  const float* Wp = (const float*)d_in[1];
  const float* W1 = (const float*)d_in[2];
  const float* b1 = (const float*)d_in[3];
  const float* W2 = (const float*)d_in[4];
  const float* b2 = (const float*)d_in[5];
  float* out = (float*)d_out;

  // ws layout: W1f [128KB] | W2f [128KB] | Wpf [32KB]
  if (ws_size < 294912) return;
  unsigned short* w1f = (unsigned short*)d_ws;
  unsigned short* w2f = (unsigned short*)((char*)d_ws + 131072);
  unsigned short* wpf = (unsigned short*)((char*)d_ws + 262144);

  prep_weights<<<72, 256, 0, stream>>>(Wp, W1, W2, wpf, w1f, w2f);
  fused_kernel<<<NBLOCKS, 256, 0, stream>>>(x, b1, b2, wpf, w1f, w2f, out);
}

// Round 3
// 247.147 us; speedup vs baseline: 1.3034x; 1.3034x over previous
//
#include <hip/hip_runtime.h>

// Problem constants
#define NROWS   200000
#define TILE    32                  // rows (n) per block
#define NBLOCKS (NROWS / TILE)      // 6250, exact

typedef __attribute__((ext_vector_type(4))) float f32x4;
typedef __attribute__((ext_vector_type(8))) short bf16x8;

// fp32 -> bf16 round-to-nearest-even (bit trick; inputs finite)
__device__ __forceinline__ unsigned short f2bf(float f) {
  unsigned b = __float_as_uint(f);
  b += 0x7fffu + ((b >> 16) & 1u);
  return (unsigned short)(b >> 16);
}
__device__ __forceinline__ unsigned pack2(float lo, float hi) {
  return (unsigned)f2bf(lo) | ((unsigned)f2bf(hi) << 16);
}
__device__ __forceinline__ float bflo(unsigned pk) { return __uint_as_float(pk << 16); }
__device__ __forceinline__ float bfhi(unsigned pk) { return __uint_as_float(pk & 0xffff0000u); }
__device__ __forceinline__ f32x4 mfma16(bf16x8 a, bf16x8 b, f32x4 c) {
  return __builtin_amdgcn_mfma_f32_16x16x32_bf16(a, b, c, 0, 0, 0);
}
__device__ __forceinline__ float fast_tanh(float x) {
  float e = __expf(2.0f * x);
  return 1.0f - __fdividef(2.0f, e + 1.0f);
}
// LDS XOR swizzle on byte offsets (uniform 256B row pitch, row = byte>>8):
// flips bits 4..6 with row&7 -> strided row-column reads spread across 8
// 16B slots (<=2-way bank aliasing = free, m136). Pure function of the
// offset -> writes and reads are always consistent. Preserves 16B alignment.
__device__ __forceinline__ int SW(int b) { return b ^ (((b >> 8) & 7) << 4); }

// ---------------------------------------------------------------------------
// Weight prep: W[K][Nout] fp32 -> bf16 MFMA-B fragments with INTERLEAVED
// column mapping: fragment (kt,nt), lane l, elem i <-
//     W[kt*32 + 8*(l>>4) + i][(nt>>1)*32 + 2*(l&15) + (nt&1)]
// Waves own tile pairs (nt=2w, 2w+1), so a lane's two D-columns are the
// ADJACENT features 32w+2*lr and 32w+2*lr+1 -> packed b32 LDS writes and
// float2 global stores downstream. h1/h2/out still land in natural order.
// ---------------------------------------------------------------------------
__global__ void prep_weights(const float* __restrict__ Wp,
                             const float* __restrict__ W1,
                             const float* __restrict__ W2,
                             unsigned short* __restrict__ wpf,
                             unsigned short* __restrict__ w1f,
                             unsigned short* __restrict__ w2f) {
  int t = blockIdx.x * 256 + threadIdx.x;   // 72*256 = 18432 = 288*64
  int q = t >> 6, l = t & 63;
  const float* W; unsigned short* dst; int NT, Nout, qb;
  if (q < 32)       { W = Wp; dst = wpf; NT = 8;  Nout = 128; qb = q; }
  else if (q < 160) { W = W1; dst = w1f; NT = 32; Nout = 512; qb = q - 32; }
  else              { W = W2; dst = w2f; NT = 8;  Nout = 128; qb = q - 160; }
  int kt = qb / NT, nt = qb % NT;
  int row0 = kt * 32 + 8 * (l >> 4);
  int col  = (nt >> 1) * 32 + 2 * (l & 15) + (nt & 1);   // interleaved
  unsigned short v[8];
#pragma unroll
  for (int i = 0; i < 8; ++i) v[i] = f2bf(W[(row0 + i) * Nout + col]);
  uint4 pack;
  pack.x = (unsigned)v[0] | ((unsigned)v[1] << 16);
  pack.y = (unsigned)v[2] | ((unsigned)v[3] << 16);
  pack.z = (unsigned)v[4] | ((unsigned)v[5] << 16);
  pack.w = (unsigned)v[6] | ((unsigned)v[7] << 16);
  *(uint4*)(dst + (size_t)(qb * 64 + l) * 8) = pack;
}

// ---------------------------------------------------------------------------
// Fused kernel. 32 rows / 256 threads (4 waves). LDS = 32768 B.
// LDS map (256B pitch, SW-swizzled):
//   [0,24576): x bf16 [96 rows'=3n+d][128]    (dead after GEMM1)
//     overlay: h1 buf0 @0 (8KB) | h1 buf1 @8192 (8KB) | h2 @16384 (8KB)
//   [24576,32768): c bf16 [32][128]
// 7 barriers total; h1 double-buffered -> 1 barrier/chunk.
// GEMM1 accumulators packed to bf16 pairs (24 VGPRs) across the MLP.
// ---------------------------------------------------------------------------
__global__ __launch_bounds__(256, 2) void fused_kernel(
    const float* __restrict__ x,
    const float* __restrict__ b1,
    const float* __restrict__ b2,
    const unsigned short* __restrict__ wpf,
    const unsigned short* __restrict__ w1f,
    const unsigned short* __restrict__ w2f,
    float* __restrict__ out) {
  __shared__ __align__(16) char smem[32768];
  const int t = threadIdx.x;
  const int l = t & 63;
  const int w = t >> 6;        // wave id (uniform per wave)
  const int lr = l & 15;
  const int lq = l >> 4;
  const long n0 = (long)blockIdx.x * TILE;

  // ---- P0: stage x -> bf16 LDS; c = sum_d x^2 in fp32 from un-rounded x.
  {
    float4 v[4][3];
#pragma unroll
    for (int k = 0; k < 4; ++k) {
      int p = t + k * 256, r = p >> 5, f = (p & 31) * 4;
      const float* xp = x + (n0 + r) * 384 + f;
      v[k][0] = *(const float4*)(xp);
      v[k][1] = *(const float4*)(xp + 128);
      v[k][2] = *(const float4*)(xp + 256);
    }
#pragma unroll
    for (int k = 0; k < 4; ++k) {
      int p = t + k * 256, r = p >> 5, f = (p & 31) * 4;
      float4 a = v[k][0], b = v[k][1], c = v[k][2];
      ushort4 s0 = { f2bf(a.x), f2bf(a.y), f2bf(a.z), f2bf(a.w) };
      ushort4 s1 = { f2bf(b.x), f2bf(b.y), f2bf(b.z), f2bf(b.w) };
      ushort4 s2 = { f2bf(c.x), f2bf(c.y), f2bf(c.z), f2bf(c.w) };
      ushort4 sc = { f2bf(a.x*a.x + b.x*b.x + c.x*c.x),
                     f2bf(a.y*a.y + b.y*b.y + c.y*c.y),
                     f2bf(a.z*a.z + b.z*b.z + c.z*c.z),
                     f2bf(a.w*a.w + b.w*b.w + c.w*c.w) };
      *(ushort4*)(smem + SW((3 * r + 0) * 256 + f * 2)) = s0;
      *(ushort4*)(smem + SW((3 * r + 1) * 256 + f * 2)) = s1;
      *(ushort4*)(smem + SW((3 * r + 2) * 256 + f * 2)) = s2;
      *(ushort4*)(smem + SW(24576 + r * 256 + f * 2))   = sc;
    }
  }
  __syncthreads();   // (1) x + c visible

  // ---- GEMM1: linx[r'][g], 96x128. Wave w owns interleaved cols
  // {32w+2*lr, 32w+2*lr+1} via tiles {2w,2w+1}. Packed to bf16 pairs.
  unsigned lx[6][4];
  {
    f32x4 acc1[6][2] = {};
#pragma unroll
    for (int kt = 0; kt < 4; ++kt) {
      bf16x8 a[6];
#pragma unroll
      for (int mt = 0; mt < 6; ++mt)
        a[mt] = *(const bf16x8*)(smem + SW((mt * 16 + lr) * 256 + kt * 64 + lq * 16));
#pragma unroll
      for (int jj = 0; jj < 2; ++jj) {
        bf16x8 b = *(const bf16x8*)(wpf + (size_t)((kt * 8 + 2 * w + jj) * 64 + l) * 8);
#pragma unroll
        for (int mt = 0; mt < 6; ++mt) acc1[mt][jj] = mfma16(a[mt], b, acc1[mt][jj]);
      }
    }
#pragma unroll
    for (int mt = 0; mt < 6; ++mt)
#pragma unroll
      for (int reg = 0; reg < 4; ++reg)
        lx[mt][reg] = pack2(acc1[mt][0][reg], acc1[mt][1][reg]);
  }

  // ---- MLP, K-chunked (128 mids/chunk), h1 double-buffered in dead-x.
  f32x4 acc3[2][2] = {};
#pragma unroll
  for (int ch = 0; ch < 4; ++ch) {
    // GEMM2 chunk: reads c only (no LDS hazard yet)
    f32x4 acc2[2][2] = {};
#pragma unroll
    for (int kt = 0; kt < 4; ++kt) {
      bf16x8 a2[2];
#pragma unroll
      for (int mt = 0; mt < 2; ++mt)
        a2[mt] = *(const bf16x8*)(smem + SW(24576 + (mt * 16 + lr) * 256 + kt * 64 + lq * 16));
#pragma unroll
      for (int jj = 0; jj < 2; ++jj) {
        bf16x8 b = *(const bf16x8*)(w1f + (size_t)((kt * 32 + ch * 8 + 2 * w + jj) * 64 + l) * 8);
#pragma unroll
        for (int mt = 0; mt < 2; ++mt) acc2[mt][jj] = mfma16(a2[mt], b, acc2[mt][jj]);
      }
    }
    if (ch == 0) __syncthreads();   // (2) GEMM1's x reads done before buf0 write
    // epilogue: bias + tanh, packed pair -> one ds_write_b32 per (mt,reg)
    const int bufb = (ch & 1) * 8192;
    float2 b1v = *(const float2*)(b1 + ch * 128 + w * 32 + 2 * lr);
#pragma unroll
    for (int mt = 0; mt < 2; ++mt)
#pragma unroll
      for (int reg = 0; reg < 4; ++reg) {
        int row = mt * 16 + 4 * lq + reg;
        unsigned pk = pack2(fast_tanh(acc2[mt][0][reg] + b1v.x),
                            fast_tanh(acc2[mt][1][reg] + b1v.y));
        *(unsigned*)(smem + SW(bufb + row * 256 + w * 64 + 4 * lr)) = pk;
      }
    __syncthreads();   // (3..6) h1 chunk visible; prev buf's reads already fenced
    // GEMM3 partial: acc3 += h1c @ W2[K-slice,:]
#pragma unroll
    for (int kt = 0; kt < 4; ++kt) {
      bf16x8 a3[2];
#pragma unroll
      for (int mt = 0; mt < 2; ++mt)
        a3[mt] = *(const bf16x8*)(smem + SW(bufb + (mt * 16 + lr) * 256 + kt * 64 + lq * 16));
#pragma unroll
      for (int jj = 0; jj < 2; ++jj) {
        bf16x8 b = *(const bf16x8*)(w2f + (size_t)(((ch * 4 + kt) * 8 + 2 * w + jj) * 64 + l) * 8);
#pragma unroll
        for (int mt = 0; mt < 2; ++mt) acc3[mt][jj] = mfma16(a3[mt], b, acc3[mt][jj]);
      }
    }
  }

  // ---- h2 = acc3 + b2 -> bf16 pairs @16384 (x rows 64..95: dead, unused)
  {
    float2 b2v = *(const float2*)(b2 + w * 32 + 2 * lr);
#pragma unroll
    for (int mt = 0; mt < 2; ++mt)
#pragma unroll
      for (int reg = 0; reg < 4; ++reg) {
        int row = mt * 16 + 4 * lq + reg;
        *(unsigned*)(smem + SW(16384 + row * 256 + w * 64 + 4 * lr)) =
            pack2(acc3[mt][0][reg] + b2v.x, acc3[mt][1][reg] + b2v.y);
      }
  }
  __syncthreads();   // (7) h2 visible

  // ---- Final: out[n,d,g] = linx * h2, float2 stores (128B segments/quad)
#pragma unroll
  for (int mt = 0; mt < 6; ++mt)
#pragma unroll
    for (int reg = 0; reg < 4; ++reg) {
      int rp = mt * 16 + 4 * lq + reg;
      int n = rp / 3;   // magic-mul
      unsigned hp = *(const unsigned*)(smem + SW(16384 + n * 256 + w * 64 + 4 * lr));
      unsigned pk = lx[mt][reg];
      float2 o = { bflo(pk) * bflo(hp), bfhi(pk) * bfhi(hp) };
      *(float2*)(out + n0 * 384 + (long)rp * 128 + w * 32 + 2 * lr) = o;
    }
}

extern "C" void kernel_launch(void* const* d_in, const int* in_sizes, int n_in,
                              void* d_out, int out_size, void* d_ws, size_t ws_size,
                              hipStream_t stream) {
  const float* x  = (const float*)d_in[0];
  const float* Wp = (const float*)d_in[1];
  const float* W1 = (const float*)d_in[2];
  const float* b1 = (const float*)d_in[3];
  const float* W2 = (const float*)d_in[4];
  const float* b2 = (const float*)d_in[5];
  float* out = (float*)d_out;

  // ws layout: W1f [128KB] | W2f [128KB] | Wpf [32KB]
  if (ws_size < 294912) return;
  unsigned short* w1f = (unsigned short*)d_ws;
  unsigned short* w2f = (unsigned short*)((char*)d_ws + 131072);
  unsigned short* wpf = (unsigned short*)((char*)d_ws + 262144);

  prep_weights<<<72, 256, 0, stream>>>(Wp, W1, W2, wpf, w1f, w2f);
  fused_kernel<<<NBLOCKS, 256, 0, stream>>>(x, b1, b2, wpf, w1f, w2f, out);
}